// Round 3
// baseline (318.671 us; speedup 1.0000x reference)
//
#include <hip/hip_runtime.h>
#include <cstddef>
#include <math.h>

// VQ layer: bf16 MFMA GEMM top-1, ZERO-BARRIER pipeline, moment-form loss.
// Structure: 1-wave (64-thread) blocks, 64 rows/wave, grid 2048.
// Codes stream as 32 chunks of 32 codes, double-buffered in LDS via
// global_load_lds; single wave per block => no s_barrier anywhere, the
// DMA->compute handoff is one counted s_waitcnt vmcnt(8) per chunk.
// Order discipline per chunk (audited): [cn loads][""-fence][stage next x8]
// [vmcnt(8)][ds_read+MFMA+pack]. cn loads are older than the 8 stage DMAs,
// so vmcnt(8) drains them too and the compiler never needs vmcnt(0) in the
// loop. ""-fences (compiler memory barriers, free) pin memory-op order so
// buffer reuse is WAR-safe: ds_reads of buf[rb] always issue before the
// stage that overwrites it, and DMA lands >=200cy after issue.
// acc = 2^21 + 2^20*(dot - 0.5*cnorm) (inputs pre-scaled by 1024);
// key = ((u32)acc<<10) + (1023 - quad*4 - cc*32 - slot), max-reduce.
// Loss via moments: [Sum x^2 - 2 Sum dot + Sum cnt*cnorm]/(N*D); dot
// recovered from winning key. Epilogue = pure codebook gather (no x re-read).
// k_final merged into k_assign via last-block pattern (threadfence + atomic
// counter + threadfence) -- one fewer kernel launch.

#define NROWS 131072
#define KC 1024
#define DD 128
#define NBLK 2048            // k_assign grid: 64 rows per 1-wave block

typedef __attribute__((ext_vector_type(8))) short short8;
typedef __attribute__((ext_vector_type(4))) float f32x4;
typedef __attribute__((ext_vector_type(4))) unsigned short u16x4;

struct WS {
  unsigned counts[KC];         // zeroed by k_prep
  unsigned blocksDone;         // zeroed by k_prep
  unsigned pad[3];
  float cnorm32[KC];
  double lossPart[NBLK];
  unsigned short chi[KC * DD]; // bf16 of (1024*c), granule-swizzled
};

static __device__ __forceinline__ unsigned short f2bf_rn(float f) {
  unsigned u = __float_as_uint(f);
  unsigned r = (u + 0x7FFFu + ((u >> 16) & 1u)) >> 16;  // RN-even
  return (unsigned short)r;
}

// prep: zero counts+counter, bf16(1024*c) + granule-swizzle, fp32 cnorms.
__global__ __launch_bounds__(128) void k_prep(const float* __restrict__ cb,
                                              WS* __restrict__ ws) {
  int gid = blockIdx.x * 128 + threadIdx.x;   // 32768 threads
  if (gid < KC) ws->counts[gid] = 0u;
  if (gid == 0) ws->blocksDone = 0u;
  int e0 = gid * 4;
  int code = e0 >> 7, k = e0 & 127;
  int g = k >> 3, j0 = k & 7;                 // granule, sub-offset
  int gs = g ^ (code & 7);                    // swizzled granule position
  int dst = code * DD + gs * 8 + j0;
  float4 c4 = *(const float4*)(cb + e0);
  float cf[4] = {c4.x, c4.y, c4.z, c4.w};
  u16x4 hv;
#pragma unroll
  for (int j = 0; j < 4; ++j) hv[j] = f2bf_rn(cf[j] * 1024.0f);
  *(u16x4*)&ws->chi[dst] = hv;
  if (gid < KC) {
    const float* cr = cb + (size_t)gid * DD;
    float a0 = 0, a1 = 0, a2 = 0, a3 = 0;
    for (int j = 0; j < DD; j += 4) {
      float4 v = *(const float4*)(cr + j);
      a0 = fmaf(v.x, v.x, a0);
      a1 = fmaf(v.y, v.y, a1);
      a2 = fmaf(v.z, v.z, a2);
      a3 = fmaf(v.w, v.w, a3);
    }
    ws->cnorm32[gid] = (a0 + a1) + (a2 + a3);
  }
}

__global__ __launch_bounds__(64, 2) void k_assign(
    const float* __restrict__ x, const float* __restrict__ cb,
    float* __restrict__ out, WS* __restrict__ ws) {
  __shared__ __align__(16) unsigned short ldsC[2][32][128];  // [buf][code][k-swz]
  __shared__ unsigned sIdx[64];

  const int lane = threadIdx.x;               // one wave per block
  const int l15 = lane & 15, quad = lane >> 4;
  const int rowbase = blockIdx.x * 64;

  // ---- stage chunk 0 -> buf 0 (flies under the x-load latency) ----
#pragma unroll
  for (int i = 0; i < 8; ++i) {
    const unsigned short* gp = ws->chi + (size_t)(i * 4) * DD + lane * 8;
    __builtin_amdgcn_global_load_lds(
        (const __attribute__((address_space(1))) unsigned int*)gp,
        (__attribute__((address_space(3))) unsigned int*)&ldsC[0][i * 4][0],
        16, 0, 0);
  }

  // ---- resident B-fragments: x_hi scaled by 1024; free Sum x^2 ----
  short8 Bh[4][4];
  float xsq = 0.0f;
#pragma unroll
  for (int Nf = 0; Nf < 4; ++Nf) {
    const float* xr = x + (size_t)(rowbase + Nf * 16 + l15) * DD;
#pragma unroll
    for (int ks = 0; ks < 4; ++ks) {
      int k0 = ks * 32 + quad * 8;
      float4 u = *(const float4*)(xr + k0);
      float4 v = *(const float4*)(xr + k0 + 4);
      float f[8] = {u.x, u.y, u.z, u.w, v.x, v.y, v.z, v.w};
      short8 bh;
#pragma unroll
      for (int j = 0; j < 8; ++j) {
        xsq = fmaf(f[j], f[j], xsq);
        bh[j] = (short)f2bf_rn(f[j] * 1024.0f);
      }
      Bh[Nf][ks] = bh;
    }
  }

  unsigned k1[4] = {0u, 0u, 0u, 0u};
  const unsigned invq = 1023u - (unsigned)(quad * 4);
  const int swz = l15 & 7;                    // read-side granule XOR
  const float* cns = ws->cnorm32;

#pragma unroll 2
  for (int cc = 0; cc < 32; ++cc) {           // 32 chunks of 32 codes
    const int rb = cc & 1, nb = rb ^ 1;
    const int nc = (cc + 1) & 31;             // cc=31 wraps (stray, WAR-safe)
    // cnorm loads FIRST (older than stage => covered by vmcnt(8))
    f32x4 cn0 = *(const f32x4*)&cns[cc * 32 + quad * 4];
    f32x4 cn1 = *(const f32x4*)&cns[cc * 32 + 16 + quad * 4];
    asm volatile("" ::: "memory");            // pin cn before stage
#pragma unroll
    for (int i = 0; i < 8; ++i) {
      const unsigned short* gp =
          ws->chi + (size_t)(nc * 32 + i * 4) * DD + lane * 8;
      __builtin_amdgcn_global_load_lds(
          (const __attribute__((address_space(1))) unsigned int*)gp,
          (__attribute__((address_space(3))) unsigned int*)&ldsC[nb][i * 4][0],
          16, 0, 0);
    }
    // <=8 outstanding == only the 8 just-issued -> cur chunk + cn done
    asm volatile("s_waitcnt vmcnt(8)" ::: "memory");

    f32x4 acc[2][4];
    f32x4 ini0, ini1;
#pragma unroll
    for (int r = 0; r < 4; ++r) {
      ini0[r] = fmaf(cn0[r], -524288.0f, 2097152.0f);
      ini1[r] = fmaf(cn1[r], -524288.0f, 2097152.0f);
    }
#pragma unroll
    for (int Nf = 0; Nf < 4; ++Nf) { acc[0][Nf] = ini0; acc[1][Nf] = ini1; }
#pragma unroll
    for (int ks = 0; ks < 4; ++ks) {
      const int goff = (((ks * 4 + quad) ^ swz) * 8);   // swizzled k-offset
      short8 A0 = *(const short8*)&ldsC[rb][l15][goff];
      short8 A1 = *(const short8*)&ldsC[rb][16 + l15][goff];
#pragma unroll
      for (int Nf = 0; Nf < 4; ++Nf) {
        acc[0][Nf] = __builtin_amdgcn_mfma_f32_16x16x32_bf16(
            A0, Bh[Nf][ks], acc[0][Nf], 0, 0, 0);
        acc[1][Nf] = __builtin_amdgcn_mfma_f32_16x16x32_bf16(
            A1, Bh[Nf][ks], acc[1][Nf], 0, 0, 0);
      }
    }
    // ---- branch-free packed-key top-1 ----
    const unsigned invqc = invq - (unsigned)(cc * 32);
#pragma unroll
    for (int Nf = 0; Nf < 4; ++Nf)
#pragma unroll
      for (int Mf = 0; Mf < 2; ++Mf)
#pragma unroll
        for (int r = 0; r < 4; ++r) {
          unsigned q = (unsigned)acc[Mf][Nf][r];          // truncating cvt
          unsigned pk = (q << 10) + (invqc - (unsigned)(Mf * 16 + r));
          k1[Nf] = max(k1[Nf], pk);
        }
  }

  // ---- cross-quad argmax merge; idx + dot recovery (moment loss) ----
  float dsum = 0.0f;
#pragma unroll
  for (int Nf = 0; Nf < 4; ++Nf) {
    unsigned a1 = k1[Nf];
    a1 = max(a1, (unsigned)__shfl_xor((int)a1, 16));
    a1 = max(a1, (unsigned)__shfl_xor((int)a1, 32));
    if (quad == 0) {
      int idx = 1023 - (int)(a1 & 1023u);     // ties -> smallest index
      sIdx[Nf * 16 + l15] = (unsigned)idx;
      atomicAdd(&ws->counts[idx], 1u);
      // acc = 2^21 + 2^20*(dot - 0.5*cn); q = floor(acc)
      float qf = (float)(a1 >> 10);
      dsum += (qf + 0.5f - 2097152.0f) * (1.0f / 1048576.0f) +
              0.5f * cns[idx];
    }
  }

  // ---- epilogue: z_st = gathered fp32 codebook rows (no x re-read) ----
  const int rh = lane >> 5;                   // 0/1: two rows per iteration
  const int seg = lane & 31;
  for (int it = 0; it < 32; ++it) {
    int r = it * 2 + rh;
    unsigned idx = sIdx[r];                   // wave-synchronous LDS RAW
    float4 c4 = *(const float4*)(cb + (size_t)idx * DD + seg * 4);
    *(float4*)(out + (size_t)(rowbase + r) * DD + seg * 4) = c4;
  }

  // ---- per-block moment partial: Sum x^2 - 2*Sum dot ----
  float v = fmaf(-2.0f, dsum, xsq);
  for (int off = 32; off; off >>= 1) v += __shfl_down(v, off);
  if (lane == 0) ws->lossPart[blockIdx.x] = (double)v;

  // ---- last-block finalize (replaces k_final kernel) ----
  __threadfence();                            // publish lossPart/out writes
  unsigned done = 0u;
  if (lane == 0) done = atomicAdd(&ws->blocksDone, 1u);
  done = (unsigned)__shfl((int)done, 0);
  if (done == NBLK - 1) {
    __threadfence();                          // invalidate L1; fresh reads
    double h = 0.0, lp = 0.0;
    for (int i = lane; i < KC; i += 64) {
      double p = (double)ws->counts[i] / (double)NROWS;
      h += p * log(p + 1e-10);
      lp += (double)ws->counts[i] * (double)ws->cnorm32[i];  // Sum cnt*cnorm
    }
    for (int i = lane; i < NBLK; i += 64) lp += ws->lossPart[i];
    for (int off = 32; off; off >>= 1) {
      h += __shfl_down(h, off);
      lp += __shfl_down(lp, off);
    }
    if (lane == 0) {
      double loss = lp / (double)((size_t)NROWS * DD);
      out[16777216] = (float)loss;
      out[16777217] = (float)loss;
      out[16777218] = (float)exp(-h);
    }
  }
}

extern "C" void kernel_launch(void* const* d_in, const int* in_sizes, int n_in,
                              void* d_out, int out_size, void* d_ws, size_t ws_size,
                              hipStream_t stream) {
  const float* x = (const float*)d_in[0];
  const float* cb = (const float*)d_in[1];
  float* out = (float*)d_out;
  WS* ws = (WS*)d_ws;

  k_prep<<<256, 128, 0, stream>>>(cb, ws);
  k_assign<<<NBLK, 64, 0, stream>>>(x, cb, out, ws);
}